// Round 1
// baseline (150.052 us; speedup 1.0000x reference)
//
#include <hip/hip_runtime.h>
#include <math.h>

// Problem constants (from reference setup_inputs)
constexpr int B = 8, N = 2048, H = 512, M = 96, S = 16;
constexpr int E = 256, D = 64, R = 5, MAXD = 600;
constexpr int NZ = 32;            // n-splits for sent max partial
constexpr int NCHUNK = N / NZ;    // 64
constexpr int MT = 8;             // mentions per block in entity kernel
constexpr float NEG_INF = -1e10f;

// ---------------------------------------------------------------------------
// K1a: partial max over token axis.  grid (H/256, B, NZ), block 256
// part[z][b][h] = max over n in chunk z of node[b][n][h]
__global__ void k_sent_partial(const float* __restrict__ node, float* __restrict__ part) {
    int h = blockIdx.x * 256 + threadIdx.x;
    int b = blockIdx.y;
    int z = blockIdx.z;
    const float* p = node + ((size_t)b * N + (size_t)z * NCHUNK) * H + h;
    float mx = -INFINITY;
    #pragma unroll 8
    for (int n = 0; n < NCHUNK; ++n) mx = fmaxf(mx, p[(size_t)n * H]);
    part[((size_t)z * B + b) * H + h] = mx;
}

// ---------------------------------------------------------------------------
// K1b: finish sent max + project onto W_score sent rows.  grid (B), block 256
// sS[b][r] = sum_h sent[b][h] * Wsc[(2E+D+h)*R + r] + b_score[r]
__global__ void k_sent_score(const float* __restrict__ part, const float* __restrict__ Wsc,
                             const float* __restrict__ bsc, float* __restrict__ sS) {
    __shared__ float sent[H];
    __shared__ float red[R][4];
    int b = blockIdx.x;
    int t = threadIdx.x;
    for (int h = t; h < H; h += 256) {
        float mx = -INFINITY;
        for (int z = 0; z < NZ; ++z) mx = fmaxf(mx, part[((size_t)z * B + b) * H + h]);
        sent[h] = mx;
    }
    __syncthreads();
    float acc[R] = {0.f, 0.f, 0.f, 0.f, 0.f};
    for (int h = t; h < H; h += 256) {
        float v = sent[h];
        const float* w = Wsc + (size_t)(2 * E + D + h) * R;
        #pragma unroll
        for (int r = 0; r < R; ++r) acc[r] += v * w[r];
    }
    int wave = t >> 6, lane = t & 63;
    #pragma unroll
    for (int r = 0; r < R; ++r) {
        float v = acc[r];
        for (int off = 32; off; off >>= 1) v += __shfl_down(v, off, 64);
        if (lane == 0) red[r][wave] = v;
    }
    __syncthreads();
    if (t < R) {
        float v = red[t][0] + red[t][1] + red[t][2] + red[t][3];
        sS[b * R + t] = v + bsc[t];
    }
}

// ---------------------------------------------------------------------------
// K2: entity span pooling + tanh-linear + projection onto W_score rows.
// grid (M/MT, B, 2) with z=0 chem / z=1 dis, block 256 (thread == e index).
// Outputs: sAB[z][b][m][r], validAB[z][b][m]
__global__ void k_entity(const float* __restrict__ node,
                         const int* __restrict__ cmap, const float* __restrict__ cmask,
                         const int* __restrict__ dmap, const float* __restrict__ dmask,
                         const float* __restrict__ Wc, const float* __restrict__ bc,
                         const float* __restrict__ Wd, const float* __restrict__ bd,
                         const float* __restrict__ Wsc,
                         float* __restrict__ sAB, float* __restrict__ validAB) {
    int mg = blockIdx.x;
    int b  = blockIdx.y;
    int z  = blockIdx.z;
    int t  = threadIdx.x;

    const int*   map  = z ? dmap  : cmap;
    const float* mask = z ? dmask : cmask;
    const float* W    = z ? Wd : Wc;
    const float* bias = z ? bd : bc;
    int scoff = z ? E : 0;

    __shared__ float pooled[MT][H];       // 16 KB
    __shared__ int   smap[MT][S];
    __shared__ float smask[MT][S];
    __shared__ float sred[4][MT * R];

    if (t < MT * S) {
        int mi = t / S, s = t % S;
        int m = mg * MT + mi;
        size_t off = ((size_t)b * M + m) * S + s;
        smap[mi][s]  = map[off];
        smask[mi][s] = mask[off];
    }
    __syncthreads();

    // masked-sum pool over span tokens, coalesced in h
    for (int h = t; h < H; h += 256) {
        #pragma unroll
        for (int mi = 0; mi < MT; ++mi) {
            float acc = 0.f;
            #pragma unroll
            for (int s = 0; s < S; ++s) {
                acc += smask[mi][s] * node[((size_t)b * N + smap[mi][s]) * H + h];
            }
            pooled[mi][h] = acc;
        }
    }
    __syncthreads();

    // e = t: dot(pooled[mi], W[:,e]) for 8 mentions, reuse each W row 8x
    float v[MT];
    {
        float acc[MT];
        #pragma unroll
        for (int mi = 0; mi < MT; ++mi) acc[mi] = 0.f;
        for (int h = 0; h < H; h += 4) {
            float w0 = W[(size_t)(h + 0) * E + t];
            float w1 = W[(size_t)(h + 1) * E + t];
            float w2 = W[(size_t)(h + 2) * E + t];
            float w3 = W[(size_t)(h + 3) * E + t];
            #pragma unroll
            for (int mi = 0; mi < MT; ++mi) {
                const float4 p4 = *reinterpret_cast<const float4*>(&pooled[mi][h]);
                acc[mi] += p4.x * w0 + p4.y * w1 + p4.z * w2 + p4.w * w3;
            }
        }
        float be = bias[t];
        #pragma unroll
        for (int mi = 0; mi < MT; ++mi) v[mi] = tanhf(acc[mi] + be);
    }

    // project onto W_score rows (scoff + e), reduce over e
    float w5[R];
    #pragma unroll
    for (int r = 0; r < R; ++r) w5[r] = Wsc[(size_t)(scoff + t) * R + r];
    int wave = t >> 6, lane = t & 63;
    #pragma unroll
    for (int mi = 0; mi < MT; ++mi) {
        #pragma unroll
        for (int r = 0; r < R; ++r) {
            float p = v[mi] * w5[r];
            for (int off = 32; off; off >>= 1) p += __shfl_down(p, off, 64);
            if (lane == 0) sred[wave][mi * R + r] = p;
        }
    }
    __syncthreads();
    if (t < MT * R) {
        float sum = sred[0][t] + sred[1][t] + sred[2][t] + sred[3][t];
        int mi = t / R, r = t % R;
        int m = mg * MT + mi;
        sAB[(((size_t)z * B + b) * M + m) * R + r] = sum;
    }
    if (t < MT) {
        float ms = 0.f;
        #pragma unroll
        for (int s = 0; s < S; ++s) ms += smask[t][s];
        int m = mg * MT + t;
        validAB[((size_t)z * B + b) * M + m] = (ms > 0.f) ? 1.f : 0.f;
    }
}

// ---------------------------------------------------------------------------
// K3: distance-value score table.  grid (MAXD), block 64 (one wave)
// sD[d][r] = sum_k dist_emb[d][k] * Wsc[(2E+k)*R + r]
__global__ void k_dist_table(const float* __restrict__ emb, const float* __restrict__ Wsc,
                             float* __restrict__ sD) {
    int d = blockIdx.x;
    int k = threadIdx.x;
    float v = emb[(size_t)d * D + k];
    #pragma unroll
    for (int r = 0; r < R; ++r) {
        float p = v * Wsc[(size_t)(2 * E + k) * R + r];
        for (int off = 32; off; off >>= 1) p += __shfl_down(p, off, 64);
        if (k == 0) sD[d * R + r] = p;
    }
}

// ---------------------------------------------------------------------------
// K4: pairwise max.  grid (B), block 256
__global__ void k_final(const int* __restrict__ distance,
                        const float* __restrict__ sAB, const float* __restrict__ validAB,
                        const float* __restrict__ sD, const float* __restrict__ sS,
                        float* __restrict__ out) {
    int b = blockIdx.x;
    int t = threadIdx.x;
    __shared__ float lA[M * R], lB[M * R];
    __shared__ float lD[MAXD * R];
    __shared__ float lvA[M], lvB[M];
    __shared__ float red[R][4];

    for (int i = t; i < M * R; i += 256) {
        lA[i] = sAB[(size_t)b * M * R + i];
        lB[i] = sAB[((size_t)(B + b)) * M * R + i];
    }
    for (int i = t; i < MAXD * R; i += 256) lD[i] = sD[i];
    for (int i = t; i < M; i += 256) {
        lvA[i] = validAB[(size_t)b * M + i];
        lvB[i] = validAB[((size_t)B + b) * M + i];
    }
    __syncthreads();

    float sSb[R];
    #pragma unroll
    for (int r = 0; r < R; ++r) sSb[r] = sS[b * R + r];
    float mx[R];
    #pragma unroll
    for (int r = 0; r < R; ++r) mx[r] = NEG_INF;

    for (int idx = t; idx < M * M; idx += 256) {
        int m = idx / M, n = idx % M;
        int dist = distance[((size_t)b * M + m) * M + n];
        bool valid = (lvA[m] > 0.f) && (lvB[n] > 0.f) && (dist >= 0 /*DIST_THRESH*/);
        if (valid) {
            #pragma unroll
            for (int r = 0; r < R; ++r) {
                float v = lA[m * R + r] + lB[n * R + r] + lD[dist * R + r] + sSb[r];
                mx[r] = fmaxf(mx[r], v);
            }
        }
    }
    int wave = t >> 6, lane = t & 63;
    #pragma unroll
    for (int r = 0; r < R; ++r) {
        float v = mx[r];
        for (int off = 32; off; off >>= 1) v = fmaxf(v, __shfl_down(v, off, 64));
        if (lane == 0) red[r][wave] = v;
    }
    __syncthreads();
    if (t < R) {
        float v = fmaxf(fmaxf(red[t][0], red[t][1]), fmaxf(red[t][2], red[t][3]));
        out[b * R + t] = v;
    }
}

// ---------------------------------------------------------------------------
extern "C" void kernel_launch(void* const* d_in, const int* in_sizes, int n_in,
                              void* d_out, int out_size, void* d_ws, size_t ws_size,
                              hipStream_t stream) {
    const float* node     = (const float*)d_in[0];
    const int*   cmap     = (const int*)  d_in[1];
    const float* cmask    = (const float*)d_in[2];
    const int*   dmap     = (const int*)  d_in[3];
    const float* dmask    = (const float*)d_in[4];
    const int*   distance = (const int*)  d_in[5];
    const float* Wc       = (const float*)d_in[6];
    const float* bc       = (const float*)d_in[7];
    const float* Wd       = (const float*)d_in[8];
    const float* bd       = (const float*)d_in[9];
    const float* Wsc      = (const float*)d_in[10];
    const float* bsc      = (const float*)d_in[11];
    const float* emb      = (const float*)d_in[12];
    float* out = (float*)d_out;

    // workspace layout (floats): total ~573 KB
    float* ws      = (float*)d_ws;
    float* part    = ws;                       // NZ*B*H   = 131072
    float* sS      = part + (size_t)NZ * B * H;      // B*R = 40
    float* sAB     = sS + B * R;               // 2*B*M*R  = 7680
    float* validAB = sAB + 2 * B * M * R;      // 2*B*M    = 1536
    float* sD      = validAB + 2 * B * M;      // MAXD*R   = 3000

    hipLaunchKernelGGL(k_sent_partial, dim3(H / 256, B, NZ), dim3(256), 0, stream, node, part);
    hipLaunchKernelGGL(k_sent_score, dim3(B), dim3(256), 0, stream, part, Wsc, bsc, sS);
    hipLaunchKernelGGL(k_entity, dim3(M / MT, B, 2), dim3(256), 0, stream,
                       node, cmap, cmask, dmap, dmask, Wc, bc, Wd, bd, Wsc, sAB, validAB);
    hipLaunchKernelGGL(k_dist_table, dim3(MAXD), dim3(64), 0, stream, emb, Wsc, sD);
    hipLaunchKernelGGL(k_final, dim3(B), dim3(256), 0, stream, distance, sAB, validAB, sD, sS, out);
}

// Round 2
// 91.755 us; speedup vs baseline: 1.6354x; 1.6354x over previous
//
#include <hip/hip_runtime.h>
#include <math.h>

// Problem constants (from reference setup_inputs)
constexpr int B = 8, N = 2048, H = 512, M = 96, S = 16;
constexpr int E = 256, D = 64, R = 5, MAXD = 600;
constexpr int NZ = 64;            // n-splits for sent max partial
constexpr int NCHUNK = N / NZ;    // 32
constexpr int MT = 8;             // mentions per block in gemm kernel
constexpr int HC = 4;             // h-chunks in gemm kernel
constexpr int HCHUNK = H / HC;    // 128
constexpr float NEG_INF = -1e10f;

// ---------------------------------------------------------------------------
// K1a: partial max over token axis.  grid (B, NZ), block 128 (thread = float4 of H)
__global__ void k_sent_partial(const float* __restrict__ node, float* __restrict__ part) {
    int t = threadIdx.x;          // float4 index, 128 covers H=512
    int b = blockIdx.x;
    int z = blockIdx.y;
    const float4* p = reinterpret_cast<const float4*>(node + ((size_t)b * N + (size_t)z * NCHUNK) * H) + t;
    float4 mx = p[0];
    #pragma unroll 8
    for (int n = 1; n < NCHUNK; ++n) {
        float4 v = p[(size_t)n * (H / 4)];
        mx.x = fmaxf(mx.x, v.x); mx.y = fmaxf(mx.y, v.y);
        mx.z = fmaxf(mx.z, v.z); mx.w = fmaxf(mx.w, v.w);
    }
    reinterpret_cast<float4*>(part + ((size_t)z * B + b) * H)[t] = mx;
}

// ---------------------------------------------------------------------------
// K1b: finish sent max + project onto W_score sent rows.  grid (B), block 256
__global__ void k_sent_score(const float* __restrict__ part, const float* __restrict__ Wsc,
                             const float* __restrict__ bsc, float* __restrict__ sS) {
    __shared__ float sent[H];
    __shared__ float red[R][4];
    int b = blockIdx.x;
    int t = threadIdx.x;
    for (int h = t; h < H; h += 256) {
        float mx = -INFINITY;
        for (int z = 0; z < NZ; ++z) mx = fmaxf(mx, part[((size_t)z * B + b) * H + h]);
        sent[h] = mx;
    }
    __syncthreads();
    float acc[R] = {0.f, 0.f, 0.f, 0.f, 0.f};
    for (int h = t; h < H; h += 256) {
        float v = sent[h];
        const float* w = Wsc + (size_t)(2 * E + D + h) * R;
        #pragma unroll
        for (int r = 0; r < R; ++r) acc[r] += v * w[r];
    }
    int wave = t >> 6, lane = t & 63;
    #pragma unroll
    for (int r = 0; r < R; ++r) {
        float v = acc[r];
        for (int off = 32; off; off >>= 1) v += __shfl_down(v, off, 64);
        if (lane == 0) red[r][wave] = v;
    }
    __syncthreads();
    if (t < R) {
        float v = red[t][0] + red[t][1] + red[t][2] + red[t][3];
        sS[b * R + t] = v + bsc[t];
    }
}

// ---------------------------------------------------------------------------
// K2a: span gather + masked-sum pool.  grid (M, B, 2), block 256 (thread = float2 of H)
// pooled[z][b][m][h]; validAB[z][b][m]
__global__ void k_pool(const float* __restrict__ node,
                       const int* __restrict__ cmap, const float* __restrict__ cmask,
                       const int* __restrict__ dmap, const float* __restrict__ dmask,
                       float* __restrict__ pooled, float* __restrict__ validAB) {
    int m = blockIdx.x, b = blockIdx.y, z = blockIdx.z;
    int t = threadIdx.x;
    const int*   map  = z ? dmap  : cmap;
    const float* mask = z ? dmask : cmask;

    __shared__ int   smap[S];
    __shared__ float smask[S];
    if (t < S) {
        size_t off = ((size_t)b * M + m) * S + t;
        smap[t]  = map[off];
        smask[t] = mask[off];
    }
    __syncthreads();

    float a0 = 0.f, a1 = 0.f;
    #pragma unroll
    for (int s = 0; s < S; ++s) {
        float mk = smask[s];
        const float2 v = reinterpret_cast<const float2*>(node + ((size_t)b * N + smap[s]) * H)[t];
        a0 += mk * v.x;
        a1 += mk * v.y;
    }
    size_t row = ((size_t)z * B + b) * M + m;
    reinterpret_cast<float2*>(pooled + row * H)[t] = make_float2(a0, a1);

    if (t == 0) {
        float ms = 0.f;
        #pragma unroll
        for (int s = 0; s < S; ++s) ms += smask[s];
        validAB[row] = (ms > 0.f) ? 1.f : 0.f;
    }
}

// ---------------------------------------------------------------------------
// K2b: partial GEMM dot[z][b][m][e] += pooled[.,hchunk] @ W[hchunk, e]
// grid (M/MT, B, 2*HC), block 256 (thread = e). atomicAdd into zeroed dot.
__global__ void k_gemm_partial(const float* __restrict__ pooled,
                               const float* __restrict__ Wc, const float* __restrict__ Wd,
                               float* __restrict__ dot) {
    int mg = blockIdx.x, b = blockIdx.y;
    int z  = blockIdx.z >> 2;
    int hc = blockIdx.z & 3;
    int t  = threadIdx.x;
    const float* W = z ? Wd : Wc;

    __shared__ float lp[MT][HCHUNK];   // 4 KB
    for (int i = t; i < MT * HCHUNK; i += 256) {
        int mi = i >> 7, hh = i & (HCHUNK - 1);
        lp[mi][hh] = pooled[(((size_t)z * B + b) * M + mg * MT + mi) * H + hc * HCHUNK + hh];
    }
    __syncthreads();

    float acc[MT];
    #pragma unroll
    for (int mi = 0; mi < MT; ++mi) acc[mi] = 0.f;

    const float* Wp = W + (size_t)(hc * HCHUNK) * E + t;
    for (int hh = 0; hh < HCHUNK; hh += 4) {
        float w0 = Wp[(size_t)(hh + 0) * E];
        float w1 = Wp[(size_t)(hh + 1) * E];
        float w2 = Wp[(size_t)(hh + 2) * E];
        float w3 = Wp[(size_t)(hh + 3) * E];
        #pragma unroll
        for (int mi = 0; mi < MT; ++mi) {
            const float4 pv = *reinterpret_cast<const float4*>(&lp[mi][hh]);
            acc[mi] += pv.x * w0 + pv.y * w1 + pv.z * w2 + pv.w * w3;
        }
    }
    #pragma unroll
    for (int mi = 0; mi < MT; ++mi) {
        size_t row = ((size_t)z * B + b) * M + mg * MT + mi;
        atomicAdd(dot + row * E + t, acc[mi]);
    }
}

// ---------------------------------------------------------------------------
// K2c: tanh + rank-R projection.  grid (2*B*M), block 64 (one wave, lane = 4 e's)
__global__ void k_tanh_proj(const float* __restrict__ dot,
                            const float* __restrict__ bc, const float* __restrict__ bd,
                            const float* __restrict__ Wsc, float* __restrict__ sAB) {
    int rid = blockIdx.x;
    int z = rid / (B * M);
    int lane = threadIdx.x;
    const float* bias = z ? bd : bc;
    int scoff = z ? E : 0;

    float4 dv = reinterpret_cast<const float4*>(dot + (size_t)rid * E)[lane];
    float4 bv = reinterpret_cast<const float4*>(bias)[lane];
    float v0 = tanhf(dv.x + bv.x);
    float v1 = tanhf(dv.y + bv.y);
    float v2 = tanhf(dv.z + bv.z);
    float v3 = tanhf(dv.w + bv.w);

    int e0 = scoff + lane * 4;
    float p[R];
    #pragma unroll
    for (int r = 0; r < R; ++r) {
        p[r] = v0 * Wsc[(size_t)(e0 + 0) * R + r] + v1 * Wsc[(size_t)(e0 + 1) * R + r]
             + v2 * Wsc[(size_t)(e0 + 2) * R + r] + v3 * Wsc[(size_t)(e0 + 3) * R + r];
    }
    #pragma unroll
    for (int r = 0; r < R; ++r) {
        for (int off = 32; off; off >>= 1) p[r] += __shfl_down(p[r], off, 64);
    }
    if (lane == 0) {
        #pragma unroll
        for (int r = 0; r < R; ++r) sAB[(size_t)rid * R + r] = p[r];
    }
}

// ---------------------------------------------------------------------------
// K3: distance-value score table.  grid (MAXD), block 64 (one wave)
__global__ void k_dist_table(const float* __restrict__ emb, const float* __restrict__ Wsc,
                             float* __restrict__ sD) {
    int d = blockIdx.x;
    int k = threadIdx.x;
    float v = emb[(size_t)d * D + k];
    #pragma unroll
    for (int r = 0; r < R; ++r) {
        float p = v * Wsc[(size_t)(2 * E + k) * R + r];
        for (int off = 32; off; off >>= 1) p += __shfl_down(p, off, 64);
        if (k == 0) sD[d * R + r] = p;
    }
}

// ---------------------------------------------------------------------------
// K4: pairwise max.  grid (B), block 256
__global__ void k_final(const int* __restrict__ distance,
                        const float* __restrict__ sAB, const float* __restrict__ validAB,
                        const float* __restrict__ sD, const float* __restrict__ sS,
                        float* __restrict__ out) {
    int b = blockIdx.x;
    int t = threadIdx.x;
    __shared__ float lA[M * R], lB[M * R];
    __shared__ float lD[MAXD * R];
    __shared__ float lvA[M], lvB[M];
    __shared__ float red[R][4];

    for (int i = t; i < M * R; i += 256) {
        lA[i] = sAB[(size_t)b * M * R + i];
        lB[i] = sAB[((size_t)(B + b)) * M * R + i];
    }
    for (int i = t; i < MAXD * R; i += 256) lD[i] = sD[i];
    for (int i = t; i < M; i += 256) {
        lvA[i] = validAB[(size_t)b * M + i];
        lvB[i] = validAB[((size_t)B + b) * M + i];
    }
    __syncthreads();

    float sSb[R];
    #pragma unroll
    for (int r = 0; r < R; ++r) sSb[r] = sS[b * R + r];
    float mx[R];
    #pragma unroll
    for (int r = 0; r < R; ++r) mx[r] = NEG_INF;

    for (int idx = t; idx < M * M; idx += 256) {
        int m = idx / M, n = idx % M;
        int dist = distance[((size_t)b * M + m) * M + n];
        bool valid = (lvA[m] > 0.f) && (lvB[n] > 0.f) && (dist >= 0 /*DIST_THRESH*/);
        if (valid) {
            #pragma unroll
            for (int r = 0; r < R; ++r) {
                float v = lA[m * R + r] + lB[n * R + r] + lD[dist * R + r] + sSb[r];
                mx[r] = fmaxf(mx[r], v);
            }
        }
    }
    int wave = t >> 6, lane = t & 63;
    #pragma unroll
    for (int r = 0; r < R; ++r) {
        float v = mx[r];
        for (int off = 32; off; off >>= 1) v = fmaxf(v, __shfl_down(v, off, 64));
        if (lane == 0) red[r][wave] = v;
    }
    __syncthreads();
    if (t < R) {
        float v = fmaxf(fmaxf(red[t][0], red[t][1]), fmaxf(red[t][2], red[t][3]));
        out[b * R + t] = v;
    }
}

// ---------------------------------------------------------------------------
extern "C" void kernel_launch(void* const* d_in, const int* in_sizes, int n_in,
                              void* d_out, int out_size, void* d_ws, size_t ws_size,
                              hipStream_t stream) {
    const float* node     = (const float*)d_in[0];
    const int*   cmap     = (const int*)  d_in[1];
    const float* cmask    = (const float*)d_in[2];
    const int*   dmap     = (const int*)  d_in[3];
    const float* dmask    = (const float*)d_in[4];
    const int*   distance = (const int*)  d_in[5];
    const float* Wc       = (const float*)d_in[6];
    const float* bc       = (const float*)d_in[7];
    const float* Wd       = (const float*)d_in[8];
    const float* bd       = (const float*)d_in[9];
    const float* Wsc      = (const float*)d_in[10];
    const float* bsc      = (const float*)d_in[11];
    const float* emb      = (const float*)d_in[12];
    float* out = (float*)d_out;

    // workspace layout (floats): total ~5.8 MB
    float* ws      = (float*)d_ws;
    float* part    = ws;                             // NZ*B*H      = 262144
    float* sS      = part + (size_t)NZ * B * H;      // B*R         = 40
    float* sAB     = sS + B * R;                     // 2*B*M*R     = 7680
    float* validAB = sAB + 2 * B * M * R;            // 2*B*M       = 1536
    float* sD      = validAB + 2 * B * M;            // MAXD*R      = 3000
    float* pooled  = sD + MAXD * R;                  // 2*B*M*H     = 786432
    float* dot     = pooled + (size_t)2 * B * M * H; // 2*B*M*E     = 393216

    hipMemsetAsync(dot, 0, (size_t)2 * B * M * E * sizeof(float), stream);

    hipLaunchKernelGGL(k_sent_partial, dim3(B, NZ), dim3(128), 0, stream, node, part);
    hipLaunchKernelGGL(k_pool, dim3(M, B, 2), dim3(256), 0, stream,
                       node, cmap, cmask, dmap, dmask, pooled, validAB);
    hipLaunchKernelGGL(k_sent_score, dim3(B), dim3(256), 0, stream, part, Wsc, bsc, sS);
    hipLaunchKernelGGL(k_gemm_partial, dim3(M / MT, B, 2 * HC), dim3(256), 0, stream,
                       pooled, Wc, Wd, dot);
    hipLaunchKernelGGL(k_dist_table, dim3(MAXD), dim3(64), 0, stream, emb, Wsc, sD);
    hipLaunchKernelGGL(k_tanh_proj, dim3(2 * B * M), dim3(64), 0, stream, dot, bc, bd, Wsc, sAB);
    hipLaunchKernelGGL(k_final, dim3(B), dim3(256), 0, stream, distance, sAB, validAB, sD, sS, out);
}